// Round 6
// baseline (457.332 us; speedup 1.0000x reference)
//
#include <hip/hip_runtime.h>

typedef _Float16 half_t;
typedef __attribute__((ext_vector_type(8))) _Float16 half8;
typedef __attribute__((ext_vector_type(4))) _Float16 half4;
typedef __attribute__((ext_vector_type(4))) float f32x4;

#define B_ 4
#define N_ 4096
#define D_ 1024
#define R_ (B_ * N_) // 16384

// ---------------------------------------------------------------------------
// async global->LDS, 16B per lane. LDS dest must be wave-uniform base + lane*16.
__device__ __forceinline__ void gload_lds16(const half_t* g, half_t* l) {
    __builtin_amdgcn_global_load_lds(
        (const __attribute__((address_space(1))) unsigned int*)g,
        (__attribute__((address_space(3))) unsigned int*)l, 16, 0, 0);
}

// raw workgroup barrier (no implicit vmcnt/lgkmcnt drain; counted vmcnt before
// it carries gload_lds->LDS visibility across waves).
__device__ __forceinline__ void wgbar() {
    asm volatile("" ::: "memory");
    __builtin_amdgcn_s_barrier();
    asm volatile("" ::: "memory");
}

// ===========================================================================
// REG-OPERAND ENGINES. Insight (R5 counters): both prior engines sit at their
// LDS-bandwidth ceiling (reads+stage-writes vs 256 B/cyc/CU), 44-60% MfmaUtil
// max. Fix: the small (L2-resident) operand's fragments load DIRECTLY from
// global into registers (line-aligned 16B/lane gathers, 2-tile-deep double
// buffer via volatile asm + counted vmcnt); only the big streamed operand is
// LDS-staged (triple buffer, 2-tile prefetch lead). LDS/tile drops to
// 64KB reads + 16KB writes = 320 cyc ~ MFMA 310 cyc -> ceiling ~97%.
// Both: 256x256 tile, BK=32, 8 waves (2M x 4N) of 128x64, acc[8][4].
// Requires: K % 64 == 0 (nk = K/32 even), nk >= 4.
// ===========================================================================

// ---- B-in-registers (Bt small: Q, final, Wvo) -----------------------------
template <int EPI, int ZSHIFT, int SWAP>
__global__ __launch_bounds__(512, 2) void gemmrgB(
    const half_t* __restrict__ A, const half_t* __restrict__ Bt,
    void* __restrict__ Cv, const float* __restrict__ bias,
    int lda, int ldb, int ldc, int K,
    long sA, long sB, long sC, float scale)
{
    __shared__ __align__(16) half_t As[3][256 * 32]; // 48 KiB triple buffer

    const int t = threadIdx.x;
    const int wave = t >> 6;
    const int lane = t & 63;
    const int l15 = lane & 15;
    const int q = lane >> 4;
    const int wm = wave >> 2;  // 0..1
    const int wn = wave & 3;   // 0..3
    const int m0 = (SWAP ? blockIdx.x : blockIdx.y) * 256;
    const int n0 = (SWAP ? blockIdx.y : blockIdx.x) * 256;
    const long zb = blockIdx.z >> ZSHIFT;
    const int zs = blockIdx.z & ((1 << ZSHIFT) - 1);

    // LDS staging (A): phys chunk c holds logical (row=c>>2, chunk=(c&3)^((c>>3)&3))
    const int c0 = t, c1 = t + 512;
    const int g0 = ((c0 & 3) ^ ((c0 >> 3) & 3)) * 8;
    const int g1 = ((c1 & 3) ^ ((c1 >> 3) & 3)) * 8;
    const half_t* Ab = A + zb * sA + (long)m0 * lda + zs * K;
    const long a0 = (long)(c0 >> 2) * lda + g0;
    const long a1 = (long)(c1 >> 2) * lda + g1;

    // B global fragment bases (per lane; 4 row-blocks of the wave's 64 cols)
    const half_t* Bb = Bt + zb * sB + (long)n0 * ldb + zs * K + q * 8;
    const half_t* bgl0 = Bb + (long)(wn * 64 +  0 + l15) * ldb;
    const half_t* bgl1 = Bb + (long)(wn * 64 + 16 + l15) * ldb;
    const half_t* bgl2 = Bb + (long)(wn * 64 + 32 + l15) * ldb;
    const half_t* bgl3 = Bb + (long)(wn * 64 + 48 + l15) * ldb;

    const int qq = (q ^ ((l15 >> 1) & 3)) * 8; // swizzled ds_read chunk

    f32x4 acc[8][4] = {};
    const int nk = K >> 5;
    half8 bf0[4], bf1[4];

#define STAGE_A(kt) do { const int kb_ = (kt) * 32; half_t* d_ = As[(kt) % 3]; \
        gload_lds16(Ab + a0 + kb_, d_ + c0 * 8);                               \
        gload_lds16(Ab + a1 + kb_, d_ + c1 * 8); } while (0)
#define BLOAD(kt, bfv) do { const long ko_ = (long)(kt) * 32;                  \
        asm volatile("global_load_dwordx4 %0, %1, off" : "=v"(bfv[0]) : "v"(bgl0 + ko_)); \
        asm volatile("global_load_dwordx4 %0, %1, off" : "=v"(bfv[1]) : "v"(bgl1 + ko_)); \
        asm volatile("global_load_dwordx4 %0, %1, off" : "=v"(bfv[2]) : "v"(bgl2 + ko_)); \
        asm volatile("global_load_dwordx4 %0, %1, off" : "=v"(bfv[3]) : "v"(bgl3 + ko_)); \
    } while (0)
    // per tile: 2 gload_lds (A) + 4 asm loads (B) = 6 vm ops. vmcnt(6) at tile
    // end retires tile kt+1's 6 (issued last tile), leaves kt+2's 6 in flight.
#define TILE(kt, BFC, BFN) do {                                                \
    if ((kt) + 2 < nk) STAGE_A((kt) + 2);                                      \
    half8 af[8];                                                               \
    _Pragma("unroll") for (int i = 0; i < 8; i++)                              \
        af[i] = *(const half8*)&As[(kt) % 3][(wm * 128 + i * 16 + l15) * 32 + qq]; \
    __builtin_amdgcn_s_setprio(1);                                             \
    _Pragma("unroll") for (int i = 0; i < 8; i++)                              \
    _Pragma("unroll") for (int j = 0; j < 4; j++)                              \
        acc[i][j] = __builtin_amdgcn_mfma_f32_16x16x32_f16(af[i], BFC[j], acc[i][j], 0, 0, 0); \
    __builtin_amdgcn_s_setprio(0);                                             \
    if ((kt) + 2 < nk) BLOAD((kt) + 2, BFC);                                   \
    if ((kt) + 2 < nk)      asm volatile("s_waitcnt vmcnt(6)" ::: "memory");   \
    else if ((kt) + 1 < nk) asm volatile("s_waitcnt vmcnt(0)" ::: "memory");   \
    __builtin_amdgcn_sched_barrier(0);                                         \
    if ((kt) + 1 < nk) wgbar();                                                \
    __builtin_amdgcn_sched_barrier(0);                                         \
} while (0)

    // prologue: tiles 0,1 (A->LDS, B->regs); retire tile 0's 6, leave tile 1's.
    STAGE_A(0); BLOAD(0, bf0);
    STAGE_A(1); BLOAD(1, bf1);
    asm volatile("s_waitcnt vmcnt(6)" ::: "memory");
    __builtin_amdgcn_sched_barrier(0);
    wgbar();
    __builtin_amdgcn_sched_barrier(0);

    for (int tt = 0; tt < nk; tt += 2) {
        TILE(tt, bf0, bf1);
        TILE(tt + 1, bf1, bf0);
    }
#undef STAGE_A
#undef BLOAD
#undef TILE

    if (EPI == 1) {
        half_t* C = (half_t*)Cv + (long)blockIdx.z * sC + (long)m0 * ldc + n0;
#pragma unroll
        for (int i = 0; i < 8; i++) {
            const int rowb = wm * 128 + i * 16 + q * 4;
#pragma unroll
            for (int j = 0; j < 4; j++) {
                const int col = wn * 64 + j * 16 + l15;
#pragma unroll
                for (int r = 0; r < 4; r++)
                    C[(long)(rowb + r) * ldc + col] = (half_t)(acc[i][j][r] * scale);
            }
        }
    } else {
        float* C = (float*)Cv + (long)blockIdx.z * sC + (long)m0 * ldc + n0;
#pragma unroll
        for (int i = 0; i < 8; i++) {
            const int rowb = wm * 128 + i * 16 + q * 4;
#pragma unroll
            for (int j = 0; j < 4; j++) {
                const int col = wn * 64 + j * 16 + l15;
                const float bv = (EPI == 2) ? bias[n0 + col] : 0.0f;
#pragma unroll
                for (int r = 0; r < 4; r++)
                    C[(long)(rowb + r) * ldc + col] = acc[i][j][r] * scale + bv;
            }
        }
    }
}

// ---- A-in-registers (A small: KV). Bt LDS-staged. -------------------------
template <int EPI, int ZSHIFT, int SWAP>
__global__ __launch_bounds__(512, 2) void gemmrgA(
    const half_t* __restrict__ A, const half_t* __restrict__ Bt,
    void* __restrict__ Cv, const float* __restrict__ bias,
    int lda, int ldb, int ldc, int K,
    long sA, long sB, long sC, float scale)
{
    __shared__ __align__(16) half_t Bs[3][256 * 32]; // 48 KiB triple buffer

    const int t = threadIdx.x;
    const int wave = t >> 6;
    const int lane = t & 63;
    const int l15 = lane & 15;
    const int q = lane >> 4;
    const int wm = wave >> 2;
    const int wn = wave & 3;
    const int m0 = (SWAP ? blockIdx.x : blockIdx.y) * 256;
    const int n0 = (SWAP ? blockIdx.y : blockIdx.x) * 256;
    const long zb = blockIdx.z >> ZSHIFT;
    const int zs = blockIdx.z & ((1 << ZSHIFT) - 1);

    const int c0 = t, c1 = t + 512;
    const int g0 = ((c0 & 3) ^ ((c0 >> 3) & 3)) * 8;
    const int g1 = ((c1 & 3) ^ ((c1 >> 3) & 3)) * 8;
    const half_t* Bb = Bt + zb * sB + (long)n0 * ldb + zs * K;
    const long b0 = (long)(c0 >> 2) * ldb + g0;
    const long b1 = (long)(c1 >> 2) * ldb + g1;

    // A global fragment base (per lane; 8 row-blocks of the wave's 128 rows)
    const half_t* apb = A + zb * sA + (long)(m0 + wm * 128 + l15) * lda + zs * K + q * 8;
    const long rstep = 16 * (long)lda;

    const int qq = (q ^ ((l15 >> 1) & 3)) * 8;

    f32x4 acc[8][4] = {};
    const int nk = K >> 5;
    half8 af0[8], af1[8];

#define STAGE_B(kt) do { const int kb_ = (kt) * 32; half_t* d_ = Bs[(kt) % 3]; \
        gload_lds16(Bb + b0 + kb_, d_ + c0 * 8);                               \
        gload_lds16(Bb + b1 + kb_, d_ + c1 * 8); } while (0)
#define ALOAD(kt, afv) do { const long ko_ = (long)(kt) * 32;                  \
        asm volatile("global_load_dwordx4 %0, %1, off" : "=v"(afv[0]) : "v"(apb + 0 * rstep + ko_)); \
        asm volatile("global_load_dwordx4 %0, %1, off" : "=v"(afv[1]) : "v"(apb + 1 * rstep + ko_)); \
        asm volatile("global_load_dwordx4 %0, %1, off" : "=v"(afv[2]) : "v"(apb + 2 * rstep + ko_)); \
        asm volatile("global_load_dwordx4 %0, %1, off" : "=v"(afv[3]) : "v"(apb + 3 * rstep + ko_)); \
        asm volatile("global_load_dwordx4 %0, %1, off" : "=v"(afv[4]) : "v"(apb + 4 * rstep + ko_)); \
        asm volatile("global_load_dwordx4 %0, %1, off" : "=v"(afv[5]) : "v"(apb + 5 * rstep + ko_)); \
        asm volatile("global_load_dwordx4 %0, %1, off" : "=v"(afv[6]) : "v"(apb + 6 * rstep + ko_)); \
        asm volatile("global_load_dwordx4 %0, %1, off" : "=v"(afv[7]) : "v"(apb + 7 * rstep + ko_)); \
    } while (0)
    // per tile: 2 gload_lds (B) + 8 asm loads (A) = 10 vm ops -> vmcnt(10).
#define TILEA(kt, AFC, AFN) do {                                               \
    if ((kt) + 2 < nk) STAGE_B((kt) + 2);                                      \
    half8 bf[4];                                                               \
    _Pragma("unroll") for (int j = 0; j < 4; j++)                              \
        bf[j] = *(const half8*)&Bs[(kt) % 3][(wn * 64 + j * 16 + l15) * 32 + qq]; \
    __builtin_amdgcn_s_setprio(1);                                             \
    _Pragma("unroll") for (int i = 0; i < 8; i++)                              \
    _Pragma("unroll") for (int j = 0; j < 4; j++)                              \
        acc[i][j] = __builtin_amdgcn_mfma_f32_16x16x32_f16(AFC[i], bf[j], acc[i][j], 0, 0, 0); \
    __builtin_amdgcn_s_setprio(0);                                             \
    if ((kt) + 2 < nk) ALOAD((kt) + 2, AFC);                                   \
    if ((kt) + 2 < nk)      asm volatile("s_waitcnt vmcnt(10)" ::: "memory");  \
    else if ((kt) + 1 < nk) asm volatile("s_waitcnt vmcnt(0)" ::: "memory");   \
    __builtin_amdgcn_sched_barrier(0);                                         \
    if ((kt) + 1 < nk) wgbar();                                                \
    __builtin_amdgcn_sched_barrier(0);                                         \
} while (0)

    STAGE_B(0); ALOAD(0, af0);
    STAGE_B(1); ALOAD(1, af1);
    asm volatile("s_waitcnt vmcnt(10)" ::: "memory");
    __builtin_amdgcn_sched_barrier(0);
    wgbar();
    __builtin_amdgcn_sched_barrier(0);

    for (int tt = 0; tt < nk; tt += 2) {
        TILEA(tt, af0, af1);
        TILEA(tt + 1, af1, af0);
    }
#undef STAGE_B
#undef ALOAD
#undef TILEA

    if (EPI == 1) {
        half_t* C = (half_t*)Cv + (long)blockIdx.z * sC + (long)m0 * ldc + n0;
#pragma unroll
        for (int i = 0; i < 8; i++) {
            const int rowb = wm * 128 + i * 16 + q * 4;
#pragma unroll
            for (int j = 0; j < 4; j++) {
                const int col = wn * 64 + j * 16 + l15;
#pragma unroll
                for (int r = 0; r < 4; r++)
                    C[(long)(rowb + r) * ldc + col] = (half_t)(acc[i][j][r] * scale);
            }
        }
    } else {
        float* C = (float*)Cv + (long)blockIdx.z * sC + (long)m0 * ldc + n0;
#pragma unroll
        for (int i = 0; i < 8; i++) {
            const int rowb = wm * 128 + i * 16 + q * 4;
#pragma unroll
            for (int j = 0; j < 4; j++) {
                const int col = wn * 64 + j * 16 + l15;
                const float bv = (EPI == 2) ? bias[n0 + col] : 0.0f;
#pragma unroll
                for (int r = 0; r < 4; r++)
                    C[(long)(rowb + r) * ldc + col] = acc[i][j][r] * scale + bv;
            }
        }
    }
}

// ===========================================================================
// LDS-both engine (R1-proven 8-phase, BK=64) — used for ctx (both operands big)
// ===========================================================================
template <int EPI, int ZSHIFT, int SWAP>
__global__ __launch_bounds__(512, 2) void gemm256(
    const half_t* __restrict__ A, const half_t* __restrict__ Bt,
    void* __restrict__ Cv, const float* __restrict__ bias,
    int lda, int ldb, int ldc, int K,
    long sA, long sB, long sC, float scale)
{
    __shared__ __align__(16) half_t As[2][2][256 * 32];
    __shared__ __align__(16) half_t Bs[2][2][256 * 32];

    const int t = threadIdx.x;
    const int wave = t >> 6;
    const int lane = t & 63;
    const int l15 = lane & 15;
    const int q = lane >> 4;
    const int wm = wave >> 2;
    const int wn = wave & 3;
    const int m0 = (SWAP ? blockIdx.x : blockIdx.y) * 256;
    const int n0 = (SWAP ? blockIdx.y : blockIdx.x) * 256;
    const long zb = blockIdx.z >> ZSHIFT;
    const int zs = blockIdx.z & ((1 << ZSHIFT) - 1);

    const int c0 = t, c1 = t + 512;
    const int r0 = c0 >> 2, r1 = c1 >> 2;
    const int g0 = ((c0 & 3) ^ ((c0 >> 3) & 3)) * 8;
    const int g1 = ((c1 & 3) ^ ((c1 >> 3) & 3)) * 8;

    const half_t* Ab = A + zb * sA + (long)m0 * lda + zs * K;
    const half_t* Bb = Bt + zb * sB + (long)n0 * ldb + zs * K;
    const long a0 = (long)r0 * lda + g0, a1 = (long)r1 * lda + g1;
    const long b0 = (long)r0 * ldb + g0, b1 = (long)r1 * ldb + g1;

    const int qq = (q ^ ((l15 >> 1) & 3)) * 8;

    f32x4 acc[8][4] = {};
    const int nk2 = K >> 6;

#define STAGE_A(tt, ks) do { const int kb_ = (tt) * 64 + (ks) * 32; \
        gload_lds16(Ab + a0 + kb_, &As[(tt) & 1][ks][c0 * 8]);      \
        gload_lds16(Ab + a1 + kb_, &As[(tt) & 1][ks][c1 * 8]); } while (0)
#define STAGE_B(tt, ks) do { const int kb_ = (tt) * 64 + (ks) * 32; \
        gload_lds16(Bb + b0 + kb_, &Bs[(tt) & 1][ks][c0 * 8]);      \
        gload_lds16(Bb + b1 + kb_, &Bs[(tt) & 1][ks][c1 * 8]); } while (0)
#define LDB4(ksb) _Pragma("unroll") \
    for (int j = 0; j < 4; j++)     \
        bf[j] = *(const half8*)&Bs[cur][ksb][(wn * 64 + j * 16 + l15) * 32 + qq];
#define LDA4(ksb, mh) _Pragma("unroll") \
    for (int i = 0; i < 4; i++)         \
        af[i] = *(const half8*)&As[cur][ksb][(wm * 128 + (mh) * 64 + i * 16 + l15) * 32 + qq];
#define MFMA16(ar) _Pragma("unroll")                    \
    for (int i = 0; i < 4; i++) _Pragma("unroll")       \
        for (int j = 0; j < 4; j++)                     \
            acc[(ar) + i][j] = __builtin_amdgcn_mfma_f32_16x16x32_f16(af[i], bf[j], acc[(ar) + i][j], 0, 0, 0);

    STAGE_A(0, 0); STAGE_B(0, 0); STAGE_A(0, 1); STAGE_B(0, 1);
    if (nk2 > 1) {
        STAGE_A(1, 0); STAGE_B(1, 0); STAGE_B(1, 1);
        asm volatile("s_waitcnt vmcnt(6)" ::: "memory");
    } else {
        asm volatile("s_waitcnt vmcnt(0)" ::: "memory");
    }
    wgbar();

    for (int tt = 0; tt < nk2; ++tt) {
        const int cur = tt & 1;
        half8 af[4], bf[4];
        LDB4(0); LDA4(0, 0);
        if (tt + 1 < nk2) STAGE_A(tt + 1, 1);
        wgbar();
        __builtin_amdgcn_s_setprio(1); MFMA16(0); __builtin_amdgcn_s_setprio(0);
        wgbar();
        LDA4(0, 1);
        if (tt + 2 < nk2) STAGE_B(tt + 2, 0);
        wgbar();
        __builtin_amdgcn_s_setprio(1); MFMA16(4); __builtin_amdgcn_s_setprio(0);
        wgbar();
        LDB4(1); LDA4(1, 0);
        if (tt + 2 < nk2) STAGE_A(tt + 2, 0);
        wgbar();
        __builtin_amdgcn_s_setprio(1); MFMA16(0); __builtin_amdgcn_s_setprio(0);
        wgbar();
        LDA4(1, 1);
        if (tt + 2 < nk2) STAGE_B(tt + 2, 1);
        wgbar();
        __builtin_amdgcn_s_setprio(1); MFMA16(4); __builtin_amdgcn_s_setprio(0);
        if (tt + 2 < nk2) asm volatile("s_waitcnt vmcnt(6)" ::: "memory");
        else              asm volatile("s_waitcnt vmcnt(0)" ::: "memory");
        wgbar();
    }
#undef STAGE_A
#undef STAGE_B
#undef LDB4
#undef LDA4
#undef MFMA16

    if (EPI == 1) {
        half_t* C = (half_t*)Cv + (long)blockIdx.z * sC + (long)m0 * ldc + n0;
#pragma unroll
        for (int a = 0; a < 8; a++) {
            const int rowb = wm * 128 + (a >> 2) * 64 + (a & 3) * 16 + q * 4;
#pragma unroll
            for (int j = 0; j < 4; j++) {
                const int col = wn * 64 + j * 16 + l15;
#pragma unroll
                for (int r = 0; r < 4; r++)
                    C[(long)(rowb + r) * ldc + col] = (half_t)(acc[a][j][r] * scale);
            }
        }
    } else {
        float* C = (float*)Cv + (long)blockIdx.z * sC + (long)m0 * ldc + n0;
#pragma unroll
        for (int a = 0; a < 8; a++) {
            const int rowb = wm * 128 + (a >> 2) * 64 + (a & 3) * 16 + q * 4;
#pragma unroll
            for (int j = 0; j < 4; j++) {
                const int col = wn * 64 + j * 16 + l15;
                const float bv = (EPI == 2) ? bias[n0 + col] : 0.0f;
#pragma unroll
                for (int r = 0; r < 4; r++)
                    C[(long)(rowb + r) * ldc + col] = acc[a][j][r] * scale + bv;
            }
        }
    }
}

// ---------------------------------------------------------------------------
// sum 4 split-K f16 partials (fp32 math) -> f16. P laid [z = b*4+s][1M halfs].
__global__ __launch_bounds__(256) void ctx_reduce_h(
    const half_t* __restrict__ P, half_t* __restrict__ ctx)
{
    const long i = ((long)blockIdx.x * 256 + threadIdx.x) * 8;
    const long b = i >> 20;
    const long idx = i & ((1L << 20) - 1);
    const half_t* p = P + (b * 4) * (1L << 20) + idx;
    const half8 s0 = *(const half8*)(p);
    const half8 s1 = *(const half8*)(p + (1L << 20));
    const half8 s2 = *(const half8*)(p + 2 * (1L << 20));
    const half8 s3 = *(const half8*)(p + 3 * (1L << 20));
    half8 o;
#pragma unroll
    for (int j = 0; j < 8; j++)
        o[j] = (half_t)((float)s0[j] + (float)s1[j] + (float)s2[j] + (float)s3[j]);
    *(half8*)(ctx + i) = o;
}

// ---------------------------------------------------------------------------
// Fused preparation, one dispatch (weight transposes + f16 converts)
__global__ __launch_bounds__(256) void prep_fused(
    const float* __restrict__ x,
    const float* __restrict__ W0, const float* __restrict__ W1,
    const float* __restrict__ W2, const float* __restrict__ W3,
    half_t* __restrict__ Wt, half_t* __restrict__ Wvh, half_t* __restrict__ Xh)
{
    const int bid = blockIdx.x;
    const int t = threadIdx.x;
    if (bid < 4096) {
        __shared__ float tile[32][33];
        const int z = bid >> 10;
        const int rem = bid & 1023;
        const int by = (rem >> 5) * 32, bx = (rem & 31) * 32;
        const float* W = z == 0 ? W0 : z == 1 ? W1 : z == 2 ? W2 : W3;
        half_t* dst = Wt + (size_t)z * 1024 * 1024;
        const int tx = t & 31, ty = t >> 5;
#pragma unroll
        for (int yy = ty; yy < 32; yy += 8)
            tile[yy][tx] = W[(long)(by + yy) * 1024 + bx + tx];
        __syncthreads();
#pragma unroll
        for (int yy = ty; yy < 32; yy += 8)
            dst[(long)(bx + yy) * 1024 + by + tx] = (half_t)tile[tx][yy];
    } else if (bid < 4608) {
        const long i = ((long)(bid - 4096) * 256 + t) * 8;
        const float4 a = *(const float4*)(W2 + i);
        const float4 b = *(const float4*)(W2 + i + 4);
        half8 o = {(half_t)a.x, (half_t)a.y, (half_t)a.z, (half_t)a.w,
                   (half_t)b.x, (half_t)b.y, (half_t)b.z, (half_t)b.w};
        *(half8*)(Wvh + i) = o;
    } else {
        const long i = ((long)(bid - 4608) * 256 + t) * 8;
        const float4 a = *(const float4*)(x + i);
        const float4 b = *(const float4*)(x + i + 4);
        half8 o = {(half_t)a.x, (half_t)a.y, (half_t)a.z, (half_t)a.w,
                   (half_t)b.x, (half_t)b.y, (half_t)b.z, (half_t)b.w};
        *(half8*)(Xh + i) = o;
    }
}

// ---------------------------------------------------------------------------
// Fused softmaxes: seq softmax (K logits -> Kt) + feature softmax (Q -> Qh)
__global__ __launch_bounds__(256) void softmax_fused(
    const half_t* __restrict__ KV, half_t* __restrict__ Kt,
    const half_t* __restrict__ Qlog, half_t* __restrict__ Qh)
{
    const int bid = blockIdx.x;
    const int t = threadIdx.x;
    if (bid < B_ * D_) {
        const long r = bid;
        const long b = r >> 10;
        const long d = r & 1023;
        const half_t* row = KV + (b * 2048 + d) * 4096;
        const half8 h0 = *(const half8*)(row + t * 16);
        const half8 h1 = *(const half8*)(row + t * 16 + 8);
        float v[16];
#pragma unroll
        for (int j = 0; j < 8; j++) { v[j] = (float)h0[j]; v[8 + j] = (float)h1[j]; }
        float m = v[0];
#pragma unroll
        for (int j = 1; j < 16; j++) m = fmaxf(m, v[j]);
#pragma unroll
        for (int o = 32; o > 0; o >>= 1) m = fmaxf(m, __shfl_xor(m, o, 64));
        __shared__ float redm[4], reds[4];
        const int wave = t >> 6;
        if ((t & 63) == 0) redm[wave] = m;
        __syncthreads();
        m = fmaxf(fmaxf(redm[0], redm[1]), fmaxf(redm[2], redm[3]));
        float s = 0.0f;
#pragma unroll
        for (int j = 0; j < 16; j++) { v[j] = __expf(v[j] - m); s += v[j]; }
#pragma unroll
        for (int o = 32; o > 0; o >>= 1) s += __shfl_xor(s, o, 64);
        if ((t & 63) == 0) reds[wave] = s;
        __syncthreads();
        s = reds[0] + reds[1] + reds[2] + reds[3];
        const float rs = 64.0f / s;
        half8 o0, o1;
#pragma unroll
        for (int j = 0; j < 8; j++) {
            o0[j] = (half_t)(v[j] * rs);
            o1[j] = (half_t)(v[8 + j] * rs);
        }
        *(half8*)(Kt + r * 4096 + t * 16) = o0;
        *(half8*)(Kt + r * 4096 + t * 16 + 8) = o1;
    } else {
        const long r = ((long)(bid - B_ * D_)) * 4 + (t >> 6);
        const int lane = t & 63;
        const half_t* row = Qlog + r * 1024 + lane * 16;
        const half8 h0 = *(const half8*)(row);
        const half8 h1 = *(const half8*)(row + 8);
        float v[16];
#pragma unroll
        for (int j = 0; j < 8; j++) { v[j] = (float)h0[j]; v[8 + j] = (float)h1[j]; }
        float m = v[0];
#pragma unroll
        for (int j = 1; j < 16; j++) m = fmaxf(m, v[j]);
#pragma unroll
        for (int o = 32; o > 0; o >>= 1) m = fmaxf(m, __shfl_xor(m, o, 64));
        float s = 0.0f;
#pragma unroll
        for (int j = 0; j < 16; j++) { v[j] = __expf(v[j] - m); s += v[j]; }
#pragma unroll
        for (int o = 32; o > 0; o >>= 1) s += __shfl_xor(s, o, 64);
        const float rs = 64.0f / s;
        half8 o0, o1;
#pragma unroll
        for (int j = 0; j < 8; j++) {
            o0[j] = (half_t)(v[j] * rs);
            o1[j] = (half_t)(v[8 + j] * rs);
        }
        half_t* orow = Qh + r * 1024 + lane * 16;
        *(half8*)(orow) = o0;
        *(half8*)(orow + 8) = o1;
    }
}

// ---------------------------------------------------------------------------
extern "C" void kernel_launch(void* const* d_in, const int* in_sizes, int n_in,
                              void* d_out, int out_size, void* d_ws, size_t ws_size,
                              hipStream_t stream)
{
    const float* x  = (const float*)d_in[0];
    const float* Wq = (const float*)d_in[1];
    const float* Wk = (const float*)d_in[2];
    const float* Wv = (const float*)d_in[3];
    const float* Wo = (const float*)d_in[4];
    const float* bo = (const float*)d_in[5];
    float* out = (float*)d_out;

    char* w = (char*)d_ws;
    half_t* Xh  = (half_t*)w;                                  // 32 MiB
    half_t* P   = (half_t*)w;                                  // 32 MiB (aliases Xh)
    w += (size_t)R_ * D_ * 2;
    half_t* KVreg = (half_t*)w;                                // 64 MiB (K | V'')
    w += (size_t)B_ * 2048 * 4096 * 2;
    half_t* Qh  = (half_t*)w; w += (size_t)R_ * D_ * 2;        // 32 MiB (q * 64)
    half_t* Kt  = (half_t*)w; w += (size_t)R_ * D_ * 2;        // 32 MiB [B,D,N] (k * 64)
    half_t* Pw  = Kt;                                          // 8 MiB scratch (pre-softmax)
    half_t* Wt  = (half_t*)w; w += (size_t)4 * D_ * D_ * 2;    // 8 MiB (Wq^T|Wk^T|Wvo^T|Wo^T)
    half_t* ctxT = (half_t*)w; w += (size_t)B_ * D_ * D_ * 2;  // 8 MiB (64 * (K^T V'')^T)
    half_t* Wvh = (half_t*)w; w += (size_t)B_ * D_ * D_ * 2;   // 2 MiB used (Wv as f16)
    half_t* Qlog = (half_t*)out;                               // 32 MiB in d_out
    (void)ws_size; (void)in_sizes; (void)n_in; (void)out_size;

    const dim3 blk(256);
    const dim3 blkg(512);
    const long M1 = 1L << 20;

    prep_fused<<<12800, blk, 0, stream>>>(x, Wq, Wk, Wv, Wo, Wt, Wvh, Xh);

    // ---- Wvo^T[o][k] = sum_e Wo^T[o,e] * Wv[k,e] (fold Wo into V path);
    // Bt = Wvh (2 MiB, L2) -> B-in-reg engine. Split-K=4 over e.
    gemmrgB<1, 2, 1><<<dim3(4, 4, 4), blkg, 0, stream>>>(Wt + 3 * M1, Wvh, Pw, nullptr,
        1024, 1024, 1024, 256, 0, 0, M1, 1.0f);
    ctx_reduce_h<<<512, blk, 0, stream>>>(Pw, Wt + 2 * M1);

    // ---- Q logits: Bt = Wt (2 MiB, L2) -> B-in-reg
    gemmrgB<1, 0, 1><<<dim3(64, 4, 1), blkg, 0, stream>>>(Xh, Wt, Qlog, nullptr,
        1024, 1024, 1024, 1024, 0, 0, 0, 1.0f);

    // ---- merged K|V'' transposed: A = Wk^T|Wvo^T slab (4 MiB, L2) -> A-in-reg
    gemmrgA<1, 0, 0><<<dim3(16, 8, B_), blkg, 0, stream>>>(Wt + M1, Xh, KVreg, nullptr,
        1024, 1024, 4096, 1024, 0, (long)N_ * D_, (long)2048 * 4096, 1.0f);

    // ---- both softmaxes in one dispatch
    softmax_fused<<<B_ * D_ + R_ / 4, blk, 0, stream>>>(KVreg, Kt, Qlog, Qh);

    // ---- ctxT[b][o][d] = sum_n v''[n,o] * (64 k[n,d]); both operands 32 MiB
    // -> LDS-both 8-phase engine. Split-K=4 over n, partials in P (Xh dead).
    gemm256<1, 2, 1><<<dim3(4, 4, 16), blkg, 0, stream>>>(KVreg + (long)1024 * 4096, Kt, P, nullptr,
        4096, 4096, 1024, N_ / 4,
        (long)2048 * 4096, (long)D_ * N_, M1, 1.0f);
    ctx_reduce_h<<<2048, blk, 0, stream>>>(P, ctxT);

    // ---- out = (q . ctxT) * 2^-25 + bo ; Bt = ctxT (2 MiB/batch, L2) -> B-in-reg
    gemmrgB<2, 0, 1><<<dim3(16, 4, B_), blkg, 0, stream>>>(Qh, ctxT, out, bo,
        1024, 1024, 1024, 1024,
        (long)N_ * D_, M1, (long)N_ * D_,
        1.0f / 33554432.0f);
}